// Round 8
// baseline (740.657 us; speedup 1.0000x reference)
//
#include <hip/hip_runtime.h>
#include <math.h>

#define NROWS 65536
#define DFULL 512
#define HHEADS 8
#define KCODES 512
#define HDIM 64
#define DELTA_S 1e-4f   // certified |d_mfma - d_xla| bound (1.7e-5) with 6x margin

// ws layout (bytes):
#define WS_LOSS  0          // double
#define WS_HIST  64         // u32[4096]
#define WS_T3    32768      // f32[4096]   XLA-exact ||c||^2
#define WS_T1    65536      // f32[N*8]    XLA-exact ||z||^2 (2MB)
#define WS_FLAG  2162688    // u8[N*8]     needs-recheck flags (512KB)
#define WS_BFRAG 2686976    // ushort[8*32*2*2*64*8] packed B-frags (1MB)

typedef short bf16x8 __attribute__((ext_vector_type(8)));
typedef float f32x4 __attribute__((ext_vector_type(4)));

// f32 -> bf16 RNE
__device__ __forceinline__ unsigned short f2bf(float f) {
    unsigned u = __float_as_uint(f);
    unsigned r = (u + 0x7FFFu + ((u >> 16) & 1u)) >> 16;
    return (unsigned short)r;
}
__device__ __forceinline__ float bf2f(unsigned short b) {
    return __uint_as_float(((unsigned)b) << 16);
}

// ---------- prep: t3 (XLA-exact sequential f32 chain) ----------
__global__ void vq_prep_t3(const float* __restrict__ cb, float* __restrict__ t3) {
    int row = blockIdx.x * blockDim.x + threadIdx.x;
    if (row >= HHEADS * KCODES) return;
    const float* c = cb + (size_t)row * HDIM;
    float s = __fmul_rn(c[0], c[0]);
    for (int i = 1; i < 64; ++i) s = __fadd_rn(s, __fmul_rn(c[i], c[i]));
    t3[row] = s;
}

// ---------- prep: t1[row*8+h] (XLA-exact sequential f32 chain) ----------
__global__ void vq_t1(const float* __restrict__ z_e, float* __restrict__ t1) {
    int t = blockIdx.x * blockDim.x + threadIdx.x;  // 524288
    int row = t >> 3, h = t & 7;
    const float* zp = z_e + (size_t)row * DFULL + (size_t)h * HDIM;
    float s = 0.0f;
    bool first = true;
    #pragma unroll
    for (int d4 = 0; d4 < 64; d4 += 4) {
        float4 v = *(const float4*)(zp + d4);
        if (first) { s = __fmul_rn(v.x, v.x); first = false; }
        else       { s = __fadd_rn(s, __fmul_rn(v.x, v.x)); }
        s = __fadd_rn(s, __fmul_rn(v.y, v.y));
        s = __fadd_rn(s, __fmul_rn(v.z, v.z));
        s = __fadd_rn(s, __fmul_rn(v.w, v.w));
    }
    t1[t] = s;
}

// ---------- prep: packed bf16-split B fragments ----------
// bfrag linear index t = h(3b) | kt(5b) | khalf(1b) | pass(1b) | lane(6b), 8 ushort each.
// B[kdim][n]: n = lane&15 (code within ktile), kdim = khalf*32 + (lane>>4)*8 + j.
__global__ void vq_prep_bfrag(const float* __restrict__ cb, unsigned short* __restrict__ bfrag) {
    int t = blockIdx.x * blockDim.x + threadIdx.x;  // 65536
    int lane = t & 63;
    int pass = (t >> 6) & 1;
    int khalf = (t >> 7) & 1;
    int kt = (t >> 8) & 31;
    int h = t >> 13;
    int n = lane & 15, kg = lane >> 4;
    int kcode = kt * 16 + n;
    int d0 = khalf * 32 + kg * 8;
    const float* src = cb + ((size_t)(h * KCODES + kcode)) * HDIM + d0;
    unsigned short o[8];
    #pragma unroll
    for (int j = 0; j < 8; ++j) {
        float v = src[j];
        unsigned short hi = f2bf(v);
        o[j] = (pass == 0) ? hi : f2bf(__fsub_rn(v, bf2f(hi)));
    }
    *(bf16x8*)(bfrag + (size_t)t * 8) = *(const bf16x8*)o;
}

// ---------- MFMA prefilter: top-2 S_k, certify or flag ----------
// S_k = dot(z,c_k) - 0.5*t3_k ; argmax_k S == argmin_k d_xla (t1 common-mode).
__global__ __launch_bounds__(256, 4) void vq_prefilter(
    const float* __restrict__ z_e, const unsigned short* __restrict__ bfrag,
    const float* __restrict__ t3,
    float* __restrict__ out_idx, unsigned char* __restrict__ flags) {
    const int l = threadIdx.x & 63;
    const int wv = threadIdx.x >> 6;
    const int h = blockIdx.x & 7;
    const int rowtile = (blockIdx.x >> 3) * 4 + wv;   // 16-row tile, 0..4095
    const size_t rowbase = (size_t)rowtile * 16;
    const int m = l & 15, kg = l >> 4;

    // A-frags: A[m][kdim], lane: row m, kdim = khalf*32 + kg*8 + j
    const float* zp = z_e + (rowbase + m) * DFULL + (size_t)h * HDIM + kg * 8;
    float zv0[8], zv1[8];
    {
        float4 a0 = *(const float4*)(zp);
        float4 a1 = *(const float4*)(zp + 4);
        float4 b0 = *(const float4*)(zp + 32);
        float4 b1 = *(const float4*)(zp + 36);
        zv0[0]=a0.x; zv0[1]=a0.y; zv0[2]=a0.z; zv0[3]=a0.w;
        zv0[4]=a1.x; zv0[5]=a1.y; zv0[6]=a1.z; zv0[7]=a1.w;
        zv1[0]=b0.x; zv1[1]=b0.y; zv1[2]=b0.z; zv1[3]=b0.w;
        zv1[4]=b1.x; zv1[5]=b1.y; zv1[6]=b1.z; zv1[7]=b1.w;
    }
    bf16x8 ah0, al0, ah1, al1;
    #pragma unroll
    for (int j = 0; j < 8; ++j) {
        unsigned short hi0 = f2bf(zv0[j]);
        ah0[j] = (short)hi0;
        al0[j] = (short)f2bf(__fsub_rn(zv0[j], bf2f(hi0)));
        unsigned short hi1 = f2bf(zv1[j]);
        ah1[j] = (short)hi1;
        al1[j] = (short)f2bf(__fsub_rn(zv1[j], bf2f(hi1)));
    }

    const float* t3h = t3 + (size_t)h * KCODES;
    const unsigned short* bf_h = bfrag + (size_t)h * 32 * 2 * 2 * 64 * 8;

    float m1[4] = {-INFINITY, -INFINITY, -INFINITY, -INFINITY};
    float m2[4] = {-INFINITY, -INFINITY, -INFINITY, -INFINITY};
    int   k1[4] = {0, 0, 0, 0};

    for (int kt = 0; kt < 32; ++kt) {
        const unsigned short* bp = bf_h + (size_t)kt * 2048;  // 2*2*64*8
        bf16x8 bh0 = *(const bf16x8*)(bp + 0 * 1024 + 0 * 512 + l * 8);
        bf16x8 bl0 = *(const bf16x8*)(bp + 0 * 1024 + 1 * 512 + l * 8);
        bf16x8 bh1 = *(const bf16x8*)(bp + 1 * 1024 + 0 * 512 + l * 8);
        bf16x8 bl1 = *(const bf16x8*)(bp + 1 * 1024 + 1 * 512 + l * 8);
        float t3v = t3h[kt * 16 + m];
        f32x4 acc;
        float ini = __fmul_rn(-0.5f, t3v);
        acc[0] = ini; acc[1] = ini; acc[2] = ini; acc[3] = ini;
        acc = __builtin_amdgcn_mfma_f32_16x16x32_bf16(ah0, bl0, acc, 0, 0, 0);
        acc = __builtin_amdgcn_mfma_f32_16x16x32_bf16(al0, bh0, acc, 0, 0, 0);
        acc = __builtin_amdgcn_mfma_f32_16x16x32_bf16(ah0, bh0, acc, 0, 0, 0);
        acc = __builtin_amdgcn_mfma_f32_16x16x32_bf16(ah1, bl1, acc, 0, 0, 0);
        acc = __builtin_amdgcn_mfma_f32_16x16x32_bf16(al1, bh1, acc, 0, 0, 0);
        acc = __builtin_amdgcn_mfma_f32_16x16x32_bf16(ah1, bh1, acc, 0, 0, 0);
        int kb = kt * 16 + m;  // col = lane&15 holds code index
        #pragma unroll
        for (int j = 0; j < 4; ++j) {
            float S = acc[j];
            bool g1 = S > m1[j];
            bool g2 = S > m2[j];
            m2[j] = g1 ? m1[j] : (g2 ? S : m2[j]);
            m1[j] = g1 ? S : m1[j];
            k1[j] = g1 ? kb : k1[j];
        }
    }

    // merge top-2 across the 16 column-lanes (xor 1,2,4,8 within group)
    #pragma unroll
    for (int off = 1; off <= 8; off <<= 1) {
        #pragma unroll
        for (int j = 0; j < 4; ++j) {
            float p1 = __shfl_xor(m1[j], off, 64);
            int   pk = __shfl_xor(k1[j], off, 64);
            float p2 = __shfl_xor(m2[j], off, 64);
            if (p1 > m1[j]) {
                m2[j] = fmaxf(m1[j], p2);
                m1[j] = p1; k1[j] = pk;
            } else {
                m2[j] = fmaxf(m2[j], p1);
            }
        }
    }

    if (m == 0) {
        #pragma unroll
        for (int j = 0; j < 4; ++j) {
            size_t row = rowbase + kg * 4 + j;          // C/D row = (l>>4)*4+j
            size_t e = row * HHEADS + h;
            out_idx[e] = (float)k1[j];
            flags[e] = ((m1[j] - m2[j]) > DELTA_S) ? 0 : 1;
        }
    }
}

// ---------- exact recheck of flagged rows (bit-exact XLA chain) ----------
__global__ __launch_bounds__(64) void vq_recheck(
    const float* __restrict__ z_e, const float* __restrict__ cb,
    const float* __restrict__ t3, const float* __restrict__ t1,
    const unsigned char* __restrict__ flags, float* __restrict__ out_idx) {
    const int lane = threadIdx.x;
    for (int e = blockIdx.x; e < NROWS * HHEADS; e += (int)gridDim.x) {
        if (!flags[e]) continue;
        int row = e >> 3, h = e & 7;
        const float* zp = z_e + (size_t)row * DFULL + (size_t)h * HDIM;
        float zr[64];
        #pragma unroll
        for (int d4 = 0; d4 < 64; d4 += 4) {
            float4 v = *(const float4*)(zp + d4);
            zr[d4+0]=v.x; zr[d4+1]=v.y; zr[d4+2]=v.z; zr[d4+3]=v.w;
        }
        float t1e = t1[e];
        const float* cbh = cb + (size_t)h * KCODES * HDIM;
        const float* t3h = t3 + (size_t)h * KCODES;
        float bd = INFINITY;
        int bk = 0x7FFFFFFF;
        for (int c = 0; c < 8; ++c) {
            int k = c * 64 + lane;
            const float* ck = cbh + (size_t)k * HDIM;
            float acc = 0.0f;
            #pragma unroll
            for (int d4 = 0; d4 < 64; d4 += 4) {
                float4 cv = *(const float4*)(ck + d4);
                acc = __fmaf_rn(zr[d4+0], cv.x, acc);
                acc = __fmaf_rn(zr[d4+1], cv.y, acc);
                acc = __fmaf_rn(zr[d4+2], cv.z, acc);
                acc = __fmaf_rn(zr[d4+3], cv.w, acc);
            }
            float dk = __fadd_rn(__fsub_rn(t1e, __fmul_rn(2.0f, acc)), t3h[k]);
            if (dk < bd) { bd = dk; bk = k; }   // ascending k -> first-index ties
        }
        #pragma unroll
        for (int off = 1; off <= 32; off <<= 1) {
            float pv = __shfl_xor(bd, off, 64);
            int   pk = __shfl_xor(bk, off, 64);
            if (pv < bd || (pv == bd && pk < bk)) { bd = pv; bk = pk; }
        }
        if (lane == 0) out_idx[e] = (float)bk;
    }
}

// ---------- gather + losses + histogram ----------
__global__ __launch_bounds__(256) void vq_gather(
    const float* __restrict__ z_e, const float* __restrict__ cb,
    const float* __restrict__ out_idx, float* __restrict__ out,
    double* __restrict__ loss_sum, unsigned* __restrict__ hist) {
    const int lane = threadIdx.x & 63;
    const int wv = threadIdx.x >> 6;
    const int h = blockIdx.x & 7;
    const int rowblk = (blockIdx.x >> 3) * 4 + wv;   // 0..1023
    const size_t rowbase = (size_t)rowblk * 64;

    int myidx = (int)out_idx[(rowbase + lane) * HHEADS + h];
    atomicAdd(&hist[h * KCODES + myidx], 1u);

    const float* cbh = cb + (size_t)h * KCODES * HDIM;
    double lsum = 0.0;
    for (int r = 0; r < 64; ++r) {
        int ir = __shfl(myidx, r, 64);
        float cv = cbh[(size_t)ir * HDIM + lane];
        size_t ro = (rowbase + r) * DFULL + (size_t)h * HDIM + lane;
        float ze = z_e[ro];
        float df = __fsub_rn(cv, ze);
        out[ro] = __fadd_rn(ze, df);   // z_e + (z_q - z_e)
        lsum += (double)df * (double)df;
    }
    #pragma unroll
    for (int off = 32; off; off >>= 1) lsum += __shfl_xor(lsum, off, 64);
    if (lane == 0) atomicAdd(loss_sum, lsum);
}

// ---------- scalars + perplexity ----------
__global__ void vq_final(const unsigned* __restrict__ hist,
                         const double* __restrict__ loss_sum,
                         float* __restrict__ out) {
    const int tid = threadIdx.x;
    const int wave = tid >> 6;
    const int lane = tid & 63;
    __shared__ double perp[HHEADS];
    double e = 0.0;
    for (int k = lane; k < KCODES; k += 64) {
        double p = (double)hist[wave * KCODES + k] / (double)NROWS;
        e += p * log(p + 1e-10);
    }
    #pragma unroll
    for (int off = 32; off; off >>= 1) e += __shfl_xor(e, off, 64);
    if (lane == 0) perp[wave] = exp(-e);
    __syncthreads();
    if (tid == 0) {
        double mm = 0.0;
        #pragma unroll
        for (int i = 0; i < HHEADS; ++i) mm += perp[i];
        mm /= (double)HHEADS;
        double S = *loss_sum;
        double cl = S / ((double)NROWS * (double)DFULL);
        size_t base = (size_t)NROWS * DFULL + (size_t)NROWS * HHEADS;
        out[base + 0] = (float)cl;
        out[base + 1] = (float)(0.1 * cl);
        out[base + 2] = (float)mm;
    }
}

extern "C" void kernel_launch(void* const* d_in, const int* in_sizes, int n_in,
                              void* d_out, int out_size, void* d_ws, size_t ws_size,
                              hipStream_t stream) {
    const float* z_e = (const float*)d_in[0];
    const float* cb  = (const float*)d_in[1];
    float* out = (float*)d_out;
    float* out_idx = out + (size_t)NROWS * DFULL;
    char* ws = (char*)d_ws;
    double* loss   = (double*)(ws + WS_LOSS);
    unsigned* hist = (unsigned*)(ws + WS_HIST);
    float* t3      = (float*)(ws + WS_T3);
    float* t1      = (float*)(ws + WS_T1);
    unsigned char* flags = (unsigned char*)(ws + WS_FLAG);
    unsigned short* bfrag = (unsigned short*)(ws + WS_BFRAG);

    hipMemsetAsync(ws, 0, WS_HIST + (size_t)HHEADS * KCODES * 4, stream);

    vq_prep_t3<<<dim3(16), dim3(256), 0, stream>>>(cb, t3);
    vq_prep_bfrag<<<dim3(256), dim3(256), 0, stream>>>(cb, bfrag);
    vq_t1<<<dim3(2048), dim3(256), 0, stream>>>(z_e, t1);
    vq_prefilter<<<dim3(8192), dim3(256), 0, stream>>>(z_e, bfrag, t3, out_idx, flags);
    vq_recheck<<<dim3(2048), dim3(64), 0, stream>>>(z_e, cb, t3, t1, flags, out_idx);
    vq_gather<<<dim3(2048), dim3(256), 0, stream>>>(z_e, cb, out_idx, out, loss, hist);
    vq_final<<<dim3(1), dim3(512), 0, stream>>>(hist, loss, out);
}

// Round 9
// 588.727 us; speedup vs baseline: 1.2581x; 1.2581x over previous
//
#include <hip/hip_runtime.h>
#include <math.h>

#define NROWS 65536
#define DFULL 512
#define HHEADS 8
#define KCODES 512
#define HDIM 64
#define DELTA_S 1e-4f   // certified |S_mfma - S_xla| bound (~8.5e-6) with 12x margin

// ws layout (bytes):
#define WS_LOSS  0          // double
#define WS_CNT   16         // u32[8] per-head worklist counts
#define WS_HIST  64         // u32[4096]
#define WS_T3    32768      // f32[4096]   XLA-exact ||c||^2
#define WS_WL    65536      // u32[8][65536] per-head worklists (2MB)
#define WS_BFRAG 2686976    // ushort[8*32*2*2*64*8] packed B-frags (1MB)

typedef short bf16x8 __attribute__((ext_vector_type(8)));
typedef float f32x4 __attribute__((ext_vector_type(4)));

// f32 -> bf16 RNE
__device__ __forceinline__ unsigned short f2bf(float f) {
    unsigned u = __float_as_uint(f);
    unsigned r = (u + 0x7FFFu + ((u >> 16) & 1u)) >> 16;
    return (unsigned short)r;
}
__device__ __forceinline__ float bf2f(unsigned short b) {
    return __uint_as_float(((unsigned)b) << 16);
}

// ---------- prep: t3 (XLA-exact sequential f32 chain) ----------
__global__ void vq_prep_t3(const float* __restrict__ cb, float* __restrict__ t3) {
    int row = blockIdx.x * blockDim.x + threadIdx.x;
    if (row >= HHEADS * KCODES) return;
    const float* c = cb + (size_t)row * HDIM;
    float s = __fmul_rn(c[0], c[0]);
    for (int i = 1; i < 64; ++i) s = __fadd_rn(s, __fmul_rn(c[i], c[i]));
    t3[row] = s;
}

// ---------- prep: packed bf16-split B fragments ----------
// t = h(3b) | kt(5b) | khalf(1b) | pass(1b) | lane(6b), 8 ushort each.
// B[kdim][n]: n = lane&15 (code in ktile), kdim = khalf*32 + (lane>>4)*8 + j.
__global__ void vq_prep_bfrag(const float* __restrict__ cb, unsigned short* __restrict__ bfrag) {
    int t = blockIdx.x * blockDim.x + threadIdx.x;  // 65536
    int lane = t & 63;
    int pass = (t >> 6) & 1;
    int khalf = (t >> 7) & 1;
    int kt = (t >> 8) & 31;
    int h = t >> 13;
    int n = lane & 15, kg = lane >> 4;
    int kcode = kt * 16 + n;
    int d0 = khalf * 32 + kg * 8;
    const float* src = cb + ((size_t)(h * KCODES + kcode)) * HDIM + d0;
    unsigned short o[8];
    #pragma unroll
    for (int j = 0; j < 8; ++j) {
        float v = src[j];
        unsigned short hi = f2bf(v);
        o[j] = (pass == 0) ? hi : f2bf(__fsub_rn(v, bf2f(hi)));
    }
    *(bf16x8*)(bfrag + (size_t)t * 8) = *(const bf16x8*)o;
}

// ---------- MFMA prefilter: top-2 S_k, certify or enqueue ----------
// S_k = dot(z,c_k) - 0.5*t3_k ; argmax_k S == argmin_k d_xla (t1 common-mode).
__global__ __launch_bounds__(256, 4) void vq_prefilter(
    const float* __restrict__ z_e, const unsigned short* __restrict__ bfrag,
    const float* __restrict__ t3,
    float* __restrict__ out_idx, unsigned* __restrict__ cnt,
    unsigned* __restrict__ wl) {
    const int l = threadIdx.x & 63;
    const int wv = threadIdx.x >> 6;
    const int h = blockIdx.x & 7;
    const int rowtile = (blockIdx.x >> 3) * 4 + wv;   // 16-row tile, 0..4095
    const size_t rowbase = (size_t)rowtile * 16;
    const int m = l & 15, kg = l >> 4;

    // A-frags: A[m][kdim], lane: row m, kdim = khalf*32 + kg*8 + j
    const float* zp = z_e + (rowbase + m) * DFULL + (size_t)h * HDIM + kg * 8;
    float zv0[8], zv1[8];
    {
        float4 a0 = *(const float4*)(zp);
        float4 a1 = *(const float4*)(zp + 4);
        float4 b0 = *(const float4*)(zp + 32);
        float4 b1 = *(const float4*)(zp + 36);
        zv0[0]=a0.x; zv0[1]=a0.y; zv0[2]=a0.z; zv0[3]=a0.w;
        zv0[4]=a1.x; zv0[5]=a1.y; zv0[6]=a1.z; zv0[7]=a1.w;
        zv1[0]=b0.x; zv1[1]=b0.y; zv1[2]=b0.z; zv1[3]=b0.w;
        zv1[4]=b1.x; zv1[5]=b1.y; zv1[6]=b1.z; zv1[7]=b1.w;
    }
    bf16x8 ah0, al0, ah1, al1;
    #pragma unroll
    for (int j = 0; j < 8; ++j) {
        unsigned short hi0 = f2bf(zv0[j]);
        ah0[j] = (short)hi0;
        al0[j] = (short)f2bf(__fsub_rn(zv0[j], bf2f(hi0)));
        unsigned short hi1 = f2bf(zv1[j]);
        ah1[j] = (short)hi1;
        al1[j] = (short)f2bf(__fsub_rn(zv1[j], bf2f(hi1)));
    }

    const float* t3h = t3 + (size_t)h * KCODES;
    const unsigned short* bf_h = bfrag + (size_t)h * 32 * 2 * 2 * 64 * 8;

    float m1[4] = {-INFINITY, -INFINITY, -INFINITY, -INFINITY};
    float m2[4] = {-INFINITY, -INFINITY, -INFINITY, -INFINITY};
    int   k1[4] = {0, 0, 0, 0};

    for (int kt = 0; kt < 32; ++kt) {
        const unsigned short* bp = bf_h + (size_t)kt * 2048;
        bf16x8 bh0 = *(const bf16x8*)(bp + 0 * 1024 + 0 * 512 + l * 8);
        bf16x8 bl0 = *(const bf16x8*)(bp + 0 * 1024 + 1 * 512 + l * 8);
        bf16x8 bh1 = *(const bf16x8*)(bp + 1 * 1024 + 0 * 512 + l * 8);
        bf16x8 bl1 = *(const bf16x8*)(bp + 1 * 1024 + 1 * 512 + l * 8);
        float t3v = t3h[kt * 16 + m];
        f32x4 acc;
        float ini = __fmul_rn(-0.5f, t3v);
        acc[0] = ini; acc[1] = ini; acc[2] = ini; acc[3] = ini;
        acc = __builtin_amdgcn_mfma_f32_16x16x32_bf16(ah0, bl0, acc, 0, 0, 0);
        acc = __builtin_amdgcn_mfma_f32_16x16x32_bf16(al0, bh0, acc, 0, 0, 0);
        acc = __builtin_amdgcn_mfma_f32_16x16x32_bf16(ah0, bh0, acc, 0, 0, 0);
        acc = __builtin_amdgcn_mfma_f32_16x16x32_bf16(ah1, bl1, acc, 0, 0, 0);
        acc = __builtin_amdgcn_mfma_f32_16x16x32_bf16(al1, bh1, acc, 0, 0, 0);
        acc = __builtin_amdgcn_mfma_f32_16x16x32_bf16(ah1, bh1, acc, 0, 0, 0);
        int kb = kt * 16 + m;  // col = lane&15 holds code index
        #pragma unroll
        for (int j = 0; j < 4; ++j) {
            float S = acc[j];
            bool g1 = S > m1[j];
            bool g2 = S > m2[j];
            m2[j] = g1 ? m1[j] : (g2 ? S : m2[j]);
            m1[j] = g1 ? S : m1[j];
            k1[j] = g1 ? kb : k1[j];
        }
    }

    // merge top-2 across the 16 column-lanes (xor 1,2,4,8 within group)
    #pragma unroll
    for (int off = 1; off <= 8; off <<= 1) {
        #pragma unroll
        for (int j = 0; j < 4; ++j) {
            float p1 = __shfl_xor(m1[j], off, 64);
            int   pk = __shfl_xor(k1[j], off, 64);
            float p2 = __shfl_xor(m2[j], off, 64);
            if (p1 > m1[j]) {
                m2[j] = fmaxf(m1[j], p2);
                m1[j] = p1; k1[j] = pk;
            } else {
                m2[j] = fmaxf(m2[j], p1);
            }
        }
    }

    // write idx; enqueue uncertified rows (wave-aggregated, one atomic/wave)
    int nf = 0;
    int frow[4];
    if (m == 0) {
        #pragma unroll
        for (int j = 0; j < 4; ++j) {
            int row = (int)rowbase + kg * 4 + j;        // C/D row = (l>>4)*4+j
            out_idx[(size_t)row * HHEADS + h] = (float)k1[j];
            if (!((m1[j] - m2[j]) > DELTA_S)) { frow[nf] = row; ++nf; }
        }
    }
    int c0 = __shfl(nf, 0, 64), c1 = __shfl(nf, 16, 64);
    int c2 = __shfl(nf, 32, 64), c3 = __shfl(nf, 48, 64);
    int tot = c0 + c1 + c2 + c3;
    int base = 0;
    if (l == 0 && tot) base = (int)atomicAdd(&cnt[h], (unsigned)tot);
    base = __shfl(base, 0, 64);
    if (m == 0 && nf) {
        int off = base + (kg > 0 ? c0 : 0) + (kg > 1 ? c1 : 0) + (kg > 2 ? c2 : 0);
        for (int i = 0; i < nf; ++i)
            wl[(size_t)h * NROWS + off + i] = (unsigned)frow[i];
    }
}

// ---------- exact recheck (bit-exact XLA chain), per-head batched ----------
// Grid: 8 heads x 128 blocks, 64 threads. Wave = 64 same-head rows, lane-per-row;
// k-loop uses block-uniform codebook addresses (codebook amortized 64x).
__global__ __launch_bounds__(64) void vq_recheck(
    const float* __restrict__ z_e, const float* __restrict__ cb,
    const float* __restrict__ t3, const unsigned* __restrict__ cnt,
    const unsigned* __restrict__ wl, float* __restrict__ out_idx) {
    const int lane = threadIdx.x;
    const int h = blockIdx.x & 7;
    const int blk = blockIdx.x >> 3;          // 0..127
    const unsigned n = cnt[h];
    const unsigned* wlh = wl + (size_t)h * NROWS;
    const float* cbh = cb + (size_t)h * KCODES * HDIM;
    const float* t3h = t3 + (size_t)h * KCODES;

    for (unsigned bs = (unsigned)blk * 64; bs < n; bs += 128u * 64u) {
        unsigned ii = bs + (unsigned)lane;
        bool act = ii < n;
        int row = (int)wlh[act ? ii : (n - 1)];

        float zr[64];
        const float* zp = z_e + (size_t)row * DFULL + (size_t)h * HDIM;
        #pragma unroll
        for (int d4 = 0; d4 < 64; d4 += 4) {
            float4 v = *(const float4*)(zp + d4);
            zr[d4+0]=v.x; zr[d4+1]=v.y; zr[d4+2]=v.z; zr[d4+3]=v.w;
        }
        // t1 inline: XLA-exact sequential ascending chain
        float t1e = __fmul_rn(zr[0], zr[0]);
        #pragma unroll
        for (int i = 1; i < 64; ++i) t1e = __fadd_rn(t1e, __fmul_rn(zr[i], zr[i]));

        float bd = INFINITY;
        int bk = 0;
        for (int k = 0; k < KCODES; ++k) {
            const float* ck = cbh + (size_t)k * HDIM;   // block-uniform
            float acc = 0.0f;
            #pragma unroll
            for (int d4 = 0; d4 < 64; d4 += 4) {
                float4 cv = *(const float4*)(ck + d4);
                acc = __fmaf_rn(zr[d4+0], cv.x, acc);
                acc = __fmaf_rn(zr[d4+1], cv.y, acc);
                acc = __fmaf_rn(zr[d4+2], cv.z, acc);
                acc = __fmaf_rn(zr[d4+3], cv.w, acc);
            }
            float dk = __fadd_rn(__fsub_rn(t1e, __fmul_rn(2.0f, acc)), t3h[k]);
            if (dk < bd) { bd = dk; bk = k; }   // ascending k -> first-index ties
        }
        if (act) out_idx[(size_t)row * HHEADS + h] = (float)bk;
    }
}

// ---------- gather + losses + histogram ----------
__global__ __launch_bounds__(256) void vq_gather(
    const float* __restrict__ z_e, const float* __restrict__ cb,
    const float* __restrict__ out_idx, float* __restrict__ out,
    double* __restrict__ loss_sum, unsigned* __restrict__ hist) {
    const int lane = threadIdx.x & 63;
    const int wv = threadIdx.x >> 6;
    const int h = blockIdx.x & 7;
    const int rowblk = (blockIdx.x >> 3) * 4 + wv;   // 0..1023
    const size_t rowbase = (size_t)rowblk * 64;

    int myidx = (int)out_idx[(rowbase + lane) * HHEADS + h];
    atomicAdd(&hist[h * KCODES + myidx], 1u);

    const float* cbh = cb + (size_t)h * KCODES * HDIM;
    double lsum = 0.0;
    for (int r = 0; r < 64; ++r) {
        int ir = __shfl(myidx, r, 64);
        float cv = cbh[(size_t)ir * HDIM + lane];
        size_t ro = (rowbase + r) * DFULL + (size_t)h * HDIM + lane;
        float ze = z_e[ro];
        float df = __fsub_rn(cv, ze);
        out[ro] = __fadd_rn(ze, df);   // z_e + (z_q - z_e)
        lsum += (double)df * (double)df;
    }
    #pragma unroll
    for (int off = 32; off; off >>= 1) lsum += __shfl_xor(lsum, off, 64);
    if (lane == 0) atomicAdd(loss_sum, lsum);
}

// ---------- scalars + perplexity ----------
__global__ void vq_final(const unsigned* __restrict__ hist,
                         const double* __restrict__ loss_sum,
                         float* __restrict__ out) {
    const int tid = threadIdx.x;
    const int wave = tid >> 6;
    const int lane = tid & 63;
    __shared__ double perp[HHEADS];
    double e = 0.0;
    for (int k = lane; k < KCODES; k += 64) {
        double p = (double)hist[wave * KCODES + k] / (double)NROWS;
        e += p * log(p + 1e-10);
    }
    #pragma unroll
    for (int off = 32; off; off >>= 1) e += __shfl_xor(e, off, 64);
    if (lane == 0) perp[wave] = exp(-e);
    __syncthreads();
    if (tid == 0) {
        double mm = 0.0;
        #pragma unroll
        for (int i = 0; i < HHEADS; ++i) mm += perp[i];
        mm /= (double)HHEADS;
        double S = *loss_sum;
        double cl = S / ((double)NROWS * (double)DFULL);
        size_t base = (size_t)NROWS * DFULL + (size_t)NROWS * HHEADS;
        out[base + 0] = (float)cl;
        out[base + 1] = (float)(0.1 * cl);
        out[base + 2] = (float)mm;
    }
}

extern "C" void kernel_launch(void* const* d_in, const int* in_sizes, int n_in,
                              void* d_out, int out_size, void* d_ws, size_t ws_size,
                              hipStream_t stream) {
    const float* z_e = (const float*)d_in[0];
    const float* cb  = (const float*)d_in[1];
    float* out = (float*)d_out;
    float* out_idx = out + (size_t)NROWS * DFULL;
    char* ws = (char*)d_ws;
    double* loss   = (double*)(ws + WS_LOSS);
    unsigned* cnt  = (unsigned*)(ws + WS_CNT);
    unsigned* hist = (unsigned*)(ws + WS_HIST);
    float* t3      = (float*)(ws + WS_T3);
    unsigned* wl   = (unsigned*)(ws + WS_WL);
    unsigned short* bfrag = (unsigned short*)(ws + WS_BFRAG);

    // zero loss + worklist counts + histogram
    hipMemsetAsync(ws, 0, WS_HIST + (size_t)HHEADS * KCODES * 4, stream);

    vq_prep_t3<<<dim3(16), dim3(256), 0, stream>>>(cb, t3);
    vq_prep_bfrag<<<dim3(256), dim3(256), 0, stream>>>(cb, bfrag);
    vq_prefilter<<<dim3(8192), dim3(256), 0, stream>>>(z_e, bfrag, t3, out_idx, cnt, wl);
    vq_recheck<<<dim3(8 * 128), dim3(64), 0, stream>>>(z_e, cb, t3, cnt, wl, out_idx);
    vq_gather<<<dim3(2048), dim3(256), 0, stream>>>(z_e, cb, out_idx, out, loss, hist);
    vq_final<<<dim3(1), dim3(512), 0, stream>>>(hist, loss, out);
}